// Round 8
// baseline (249.131 us; speedup 1.0000x reference)
//
#include <hip/hip_runtime.h>

typedef short short8 __attribute__((ext_vector_type(8)));
typedef float floatx4 __attribute__((ext_vector_type(4)));
typedef _Float16 half2v __attribute__((ext_vector_type(2)));

#define Hh 128
#define Ww 256
#define Cc 64
#define COUT 64
#define Bb 4
#define HW (Hh*Ww)
#define VP 74   // LDS V row stride in shorts: 37 dwords ≡ 5 (mod 32) -> <=2-way (free)

__device__ inline unsigned bf16rne(float f) {
    unsigned u = __float_as_uint(f);
    return (u + 0x7FFF + ((u >> 16) & 1)) >> 16;
}

// weight (o, c, kt) fp32 -> Wb[kt][o][c] bf16 (A-operand friendly: c contiguous)
__global__ void wtrans(const float* __restrict__ src, unsigned short* __restrict__ dst) {
    int i = blockIdx.x * 256 + threadIdx.x;
    if (i >= COUT * Cc * 9) return;
    int kt = i % 9, c = (i / 9) % Cc, o = i / (9 * Cc);
    dst[(kt * COUT + o) * Cc + c] = (unsigned short)bf16rne(src[i]);
}

// x NCHW fp32 -> NHWC fp16. One block per (h,b) row; LDS stride 74 shorts
// (37 dwords, odd) -> conflict-free write phase.
__global__ void xtrans(const float* __restrict__ src, _Float16* __restrict__ dst) {
    __shared__ unsigned short T[256][VP];
    const int h = blockIdx.x, b = blockIdx.y;
    const int tid = threadIdx.x;
    const float* sp = src + (b * Cc * Hh + h) * Ww + tid;   // x[b][.][h][tid]
#pragma unroll
    for (int c2 = 0; c2 < 32; ++c2) {
        const float v0 = sp[(2 * c2) * HW];
        const float v1 = sp[(2 * c2 + 1) * HW];
        half2v hv; hv.x = (_Float16)v0; hv.y = (_Float16)v1;
        *(unsigned*)&T[tid][2 * c2] = *(unsigned*)&hv;
    }
    __syncthreads();
    uint4* drow = (uint4*)(dst + ((size_t)(b * Hh + h) * Ww) * 64);  // 2048 uint4
#pragma unroll
    for (int j = 0; j < 8; ++j) {
        const int idx = j * 256 + tid;        // contiguous 4KB per iteration
        drow[idx] = *(const uint4*)&T[idx >> 3][(idx & 7) * 8];
    }
}

struct Tap {
    float w00, w01, w10, w11;
    int a00, a01, a10, a11;   // corner addresses in uint4 (16B) units
};

// dy/dx come pre-loaded (prefetched one tap ahead) -> no serial load here
__device__ inline void tap_setup(int kt, int h, int w, float dy, float dx,
                                 int cg, Tap& t) {
    const int ki = kt / 3, kj = kt % 3;
    const float py = (float)(h - 1 + ki) + dy;
    const float px = (float)(w - 1 + kj) + dx;
    const float y0f = floorf(py), x0f = floorf(px);
    const int y0 = (int)y0f, x0 = (int)x0f;
    const float ly = py - y0f, lx = px - x0f;
    const int y1 = y0 + 1, x1 = x0 + 1;
    const bool vy0 = ((unsigned)y0 < Hh), vy1 = ((unsigned)y1 < Hh);
    const bool vx0 = ((unsigned)x0 < Ww), vx1 = ((unsigned)x1 < Ww);
    t.w00 = (vy0 && vx0) ? (1.f - ly) * (1.f - lx) : 0.f;
    t.w01 = (vy0 && vx1) ? (1.f - ly) * lx : 0.f;
    t.w10 = (vy1 && vx0) ? ly * (1.f - lx) : 0.f;
    t.w11 = (vy1 && vx1) ? ly * lx : 0.f;
    const int y0c = min(max(y0, 0), Hh - 1), y1c = min(max(y1, 0), Hh - 1);
    const int x0c = min(max(x0, 0), Ww - 1), x1c = min(max(x1, 0), Ww - 1);
    t.a00 = (y0c * Ww + x0c) * 8 + cg * 2;   // 64ch*2B = 8 uint4/pos; cg chunk = 2
    t.a01 = (y0c * Ww + x1c) * 8 + cg * 2;
    t.a10 = (y1c * Ww + x0c) * 8 + cg * 2;
    t.a11 = (y1c * Ww + x1c) * 8 + cg * 2;
}

// 8 x 16B loads: 4 adjacent lanes (same p, cg=0..3) cover contiguous 128B rows
__device__ inline void tap_load(const uint4* __restrict__ xb4, const Tap& t,
                                unsigned pf[32]) {
#pragma unroll
    for (int j = 0; j < 2; ++j) {
        *(uint4*)&pf[(0 * 2 + j) * 4] = xb4[t.a00 + j];
        *(uint4*)&pf[(1 * 2 + j) * 4] = xb4[t.a01 + j];
        *(uint4*)&pf[(2 * 2 + j) * 4] = xb4[t.a10 + j];
        *(uint4*)&pf[(3 * 2 + j) * 4] = xb4[t.a11 + j];
    }
}

__device__ inline void tap_store(const Tap& t, const unsigned pf[32],
                                 unsigned short* __restrict__ vrow) {
#pragma unroll
    for (int j = 0; j < 2; ++j) {
        unsigned o[4];
#pragma unroll
        for (int s = 0; s < 4; ++s) {
            const half2v h00 = *(const half2v*)&pf[(0 * 2 + j) * 4 + s];
            const half2v h01 = *(const half2v*)&pf[(1 * 2 + j) * 4 + s];
            const half2v h10 = *(const half2v*)&pf[(2 * 2 + j) * 4 + s];
            const half2v h11 = *(const half2v*)&pf[(3 * 2 + j) * 4 + s];
            const float vlo = t.w00 * (float)h00.x + t.w01 * (float)h01.x
                            + t.w10 * (float)h10.x + t.w11 * (float)h11.x;
            const float vhi = t.w00 * (float)h00.y + t.w01 * (float)h01.y
                            + t.w10 * (float)h10.y + t.w11 * (float)h11.y;
            o[s] = bf16rne(vlo) | (bf16rne(vhi) << 16);
        }
        uint4 u; u.x = o[0]; u.y = o[1]; u.z = o[2]; u.w = o[3];
        *(uint4*)(vrow + j * 8) = u;   // ds_write_b128
    }
}

__device__ inline void mfma_tap(const unsigned short* __restrict__ wk,
                                const unsigned short* __restrict__ Vbuf,
                                int wv, int ln, floatx4 acc[4]) {
#pragma unroll
    for (int g = 0; g < 2; ++g) {
        const int pp = wv * 16 + (ln & 15);
        short8 bfrag = *(const short8*)&Vbuf[pp * VP + g * 32 + (ln >> 4) * 8];
#pragma unroll
        for (int mt = 0; mt < 4; ++mt) {
            const int oo = mt * 16 + (ln & 15);
            short8 afrag = *(const short8*)(wk + oo * Cc + g * 32 + (ln >> 4) * 8);
            acc[mt] = __builtin_amdgcn_mfma_f32_16x16x32_bf16(afrag, bfrag, acc[mt], 0, 0, 0);
        }
    }
}

// Implicit GEMM, 64-pos tiles (2048 blocks = exactly 8/CU, all resident),
// software-pipelined taps w/ double-buffered LDS V + one-tap-ahead offset
// prefetch. 8 blocks/CU: LDS 8x18.9KB=151.5KB <= 160KB; unified reg budget
// 64/wave (R7 measured 40 VGPR + 16 AGPR = 56; +4 offset prefetch ~ 60).
__launch_bounds__(256, 8)
__global__ void dcn_mfma(const _Float16* __restrict__ xn,   // NHWC fp16
                         const float* __restrict__ offset,
                         const unsigned short* __restrict__ wb,
                         const float* __restrict__ bias,
                         float* __restrict__ out) {
    __shared__ unsigned short V[2][64 * VP];   // 2 x 9472 B

    const int tid = threadIdx.x;
    const int p   = tid >> 2;     // position (gather role): 4 lanes share one pos
    const int cg  = tid & 3;      // channel chunk 16ch = 32B
    const int wv  = tid >> 6;     // wave id (MFMA role: n-tile wv)
    const int ln  = tid & 63;

    const int b  = blockIdx.z;
    const int h  = blockIdx.y;
    const int w0 = blockIdx.x * 64;
    const int w  = w0 + p;

    const uint4* xb4  = (const uint4*)(xn + (size_t)b * HW * 64);
    const float* offb = offset + b * 18 * HW + h * Ww + w;
    unsigned short* vrow0 = &V[0][p * VP + cg * 16];
    unsigned short* vrow1 = &V[1][p * VP + cg * 16];

    floatx4 acc[4];
#pragma unroll
    for (int mt = 0; mt < 4; ++mt) acc[mt] = (floatx4)0.f;

    unsigned pf[32];
    Tap t;

    // prologue: tap 0 (offset loads + gather exposed once)
    float dy = offb[0];
    float dx = offb[HW];
    // prefetch tap 1 offsets while tap 0 proceeds
    float ndy = offb[2 * HW];
    float ndx = offb[3 * HW];
    tap_setup(0, h, w, dy, dx, cg, t);
    tap_load(xb4, t, pf);
    tap_store(t, pf, vrow0);
    __syncthreads();

    // pipeline: prefetch offsets kt+1, issue gathers kt, MFMA kt-1, pack kt
#pragma unroll 1
    for (int kt = 1; kt < 9; ++kt) {
        dy = ndy; dx = ndx;
        if (kt < 8) {
            ndy = offb[(2 * kt + 2) * HW];   // in flight across this whole tap
            ndx = offb[(2 * kt + 3) * HW];
        }
        tap_setup(kt, h, w, dy, dx, cg, t);
        tap_load(xb4, t, pf);                              // gathers in flight
        mfma_tap(wb + (kt - 1) * COUT * Cc, V[(kt - 1) & 1], wv, ln, acc);
        tap_store(t, pf, (kt & 1) ? vrow1 : vrow0);        // waits gathers here
        __syncthreads();
    }
    // epilogue: tap 8 MFMA (buffer 0)
    mfma_tap(wb + 8 * COUT * Cc, V[0], wv, ln, acc);

    // epilogue: C/D layout col=lane&15 (pos), row=(lane>>4)*4+reg (o)
    float* outp = out + b * COUT * HW + h * Ww;
    const int col = w0 + wv * 16 + (ln & 15);
#pragma unroll
    for (int mt = 0; mt < 4; ++mt)
#pragma unroll
        for (int r = 0; r < 4; ++r) {
            const int o = mt * 16 + (ln >> 4) * 4 + r;
            outp[o * HW + col] = acc[mt][r] + bias[o];
        }
}

extern "C" void kernel_launch(void* const* d_in, const int* in_sizes, int n_in,
                              void* d_out, int out_size, void* d_ws, size_t ws_size,
                              hipStream_t stream) {
    const float* x      = (const float*)d_in[0];
    const float* offset = (const float*)d_in[1];
    const float* weight = (const float*)d_in[2];
    const float* bias   = (const float*)d_in[3];
    float* out = (float*)d_out;

    _Float16* xn = (_Float16*)d_ws;                          // 16.8 MiB NHWC fp16
    unsigned short* wb = (unsigned short*)((char*)d_ws + (size_t)Bb * HW * Cc * 2);

    wtrans<<<dim3((COUT * Cc * 9 + 255) / 256), 256, 0, stream>>>(weight, wb);
    xtrans<<<dim3(Hh, Bb), 256, 0, stream>>>(x, xn);
    dcn_mfma<<<dim3(Ww / 64, Hh, Bb), 256, 0, stream>>>(xn, offset, wb, bias, out);
}

// Round 9
// 181.291 us; speedup vs baseline: 1.3742x; 1.3742x over previous
//
#include <hip/hip_runtime.h>

typedef short short8 __attribute__((ext_vector_type(8)));
typedef float floatx4 __attribute__((ext_vector_type(4)));
typedef _Float16 half2v __attribute__((ext_vector_type(2)));

#define Hh 128
#define Ww 256
#define Cc 64
#define COUT 64
#define Bb 4
#define HW (Hh*Ww)
#define VP 74   // LDS V row stride in shorts: 37 dwords ≡ 5 (mod 32) -> <=2-way (free)

__device__ inline unsigned bf16rne(float f) {
    unsigned u = __float_as_uint(f);
    return (u + 0x7FFF + ((u >> 16) & 1)) >> 16;
}

// weight (o, c, kt) fp32 -> Wb[kt][o][c] bf16 (A-operand friendly: c contiguous)
__global__ void wtrans(const float* __restrict__ src, unsigned short* __restrict__ dst) {
    int i = blockIdx.x * 256 + threadIdx.x;
    if (i >= COUT * Cc * 9) return;
    int kt = i % 9, c = (i / 9) % Cc, o = i / (9 * Cc);
    dst[(kt * COUT + o) * Cc + c] = (unsigned short)bf16rne(src[i]);
}

// x NCHW fp32 -> NHWC fp16. Block = (wh, h, b): 128 positions x 64 ch.
// 1024 blocks (4/CU); per-thread 16 strided reads, 4 coalesced uint4 writes.
__global__ void xtrans(const float* __restrict__ src, _Float16* __restrict__ dst) {
    __shared__ unsigned short T[128][VP];
    const int wh = blockIdx.x, h = blockIdx.y, b = blockIdx.z;
    const int tid = threadIdx.x;
    const int wl = tid & 127;           // position within half-row
    const int ch = tid >> 7;            // channel half (32 ch each)
    const float* sp = src + ((b * Cc + ch * 32) * Hh + h) * Ww + wh * 128 + wl;
#pragma unroll
    for (int c2 = 0; c2 < 16; ++c2) {
        const float v0 = sp[(2 * c2) * HW];
        const float v1 = sp[(2 * c2 + 1) * HW];
        half2v hv; hv.x = (_Float16)v0; hv.y = (_Float16)v1;
        *(unsigned*)&T[wl][ch * 32 + 2 * c2] = *(unsigned*)&hv;
    }
    __syncthreads();
    uint4* drow = (uint4*)(dst + ((size_t)(b * Hh + h) * Ww + wh * 128) * 64);  // 1024 uint4
#pragma unroll
    for (int j = 0; j < 4; ++j) {
        const int idx = j * 256 + tid;        // contiguous 4KB per iteration
        drow[idx] = *(const uint4*)&T[idx >> 3][(idx & 7) * 8];
    }
}

struct Tap {
    float w00, w01, w10, w11;
    int a00, a01, a10, a11;   // corner addresses in uint4 (16B) units
};

// dy/dx come pre-loaded (prefetched one tap ahead) -> no serial load here
__device__ inline void tap_setup(int kt, int h, int w, float dy, float dx,
                                 int cg, Tap& t) {
    const int ki = kt / 3, kj = kt % 3;
    const float py = (float)(h - 1 + ki) + dy;
    const float px = (float)(w - 1 + kj) + dx;
    const float y0f = floorf(py), x0f = floorf(px);
    const int y0 = (int)y0f, x0 = (int)x0f;
    const float ly = py - y0f, lx = px - x0f;
    const int y1 = y0 + 1, x1 = x0 + 1;
    const bool vy0 = ((unsigned)y0 < Hh), vy1 = ((unsigned)y1 < Hh);
    const bool vx0 = ((unsigned)x0 < Ww), vx1 = ((unsigned)x1 < Ww);
    t.w00 = (vy0 && vx0) ? (1.f - ly) * (1.f - lx) : 0.f;
    t.w01 = (vy0 && vx1) ? (1.f - ly) * lx : 0.f;
    t.w10 = (vy1 && vx0) ? ly * (1.f - lx) : 0.f;
    t.w11 = (vy1 && vx1) ? ly * lx : 0.f;
    const int y0c = min(max(y0, 0), Hh - 1), y1c = min(max(y1, 0), Hh - 1);
    const int x0c = min(max(x0, 0), Ww - 1), x1c = min(max(x1, 0), Ww - 1);
    t.a00 = (y0c * Ww + x0c) * 8 + cg;   // 64ch*2B = 8 uint4/pos; cg = 1 uint4 (8ch)
    t.a01 = (y0c * Ww + x1c) * 8 + cg;
    t.a10 = (y1c * Ww + x0c) * 8 + cg;
    t.a11 = (y1c * Ww + x1c) * 8 + cg;
}

// 4 x 16B loads: 8 adjacent lanes (same p, cg=0..7) cover a contiguous 128B row
__device__ inline void tap_load(const uint4* __restrict__ xb4, const Tap& t,
                                unsigned pf[16]) {
    *(uint4*)&pf[0]  = xb4[t.a00];
    *(uint4*)&pf[4]  = xb4[t.a01];
    *(uint4*)&pf[8]  = xb4[t.a10];
    *(uint4*)&pf[12] = xb4[t.a11];
}

__device__ inline void tap_store(const Tap& t, const unsigned pf[16],
                                 unsigned short* __restrict__ vrow) {
    unsigned o[4];
#pragma unroll
    for (int s = 0; s < 4; ++s) {
        const half2v h00 = *(const half2v*)&pf[s];
        const half2v h01 = *(const half2v*)&pf[4 + s];
        const half2v h10 = *(const half2v*)&pf[8 + s];
        const half2v h11 = *(const half2v*)&pf[12 + s];
        const float vlo = t.w00 * (float)h00.x + t.w01 * (float)h01.x
                        + t.w10 * (float)h10.x + t.w11 * (float)h11.x;
        const float vhi = t.w00 * (float)h00.y + t.w01 * (float)h01.y
                        + t.w10 * (float)h10.y + t.w11 * (float)h11.y;
        o[s] = bf16rne(vlo) | (bf16rne(vhi) << 16);
    }
    uint4 u; u.x = o[0]; u.y = o[1]; u.z = o[2]; u.w = o[3];
    *(uint4*)vrow = u;   // single ds_write_b128 (8 channels)
}

// Wave wv: n-tile nt = wv&1 (16 pos), m-tiles (wv>>1)*2 + {0,1}
__device__ inline void mfma_tap(const unsigned short* __restrict__ wk,
                                const unsigned short* __restrict__ Vbuf,
                                int wv, int ln, floatx4 acc[2]) {
    const int nt = wv & 1;
    const int mb = (wv >> 1) * 2;
#pragma unroll
    for (int g = 0; g < 2; ++g) {
        const int pp = nt * 16 + (ln & 15);
        short8 bfrag = *(const short8*)&Vbuf[pp * VP + g * 32 + (ln >> 4) * 8];
#pragma unroll
        for (int mi = 0; mi < 2; ++mi) {
            const int oo = (mb + mi) * 16 + (ln & 15);
            short8 afrag = *(const short8*)(wk + oo * Cc + g * 32 + (ln >> 4) * 8);
            acc[mi] = __builtin_amdgcn_mfma_f32_16x16x32_bf16(afrag, bfrag, acc[mi], 0, 0, 0);
        }
    }
}

// Implicit GEMM, 32-pos tiles (4096 blocks, 8 resident/CU), software-pipelined
// taps w/ double-buffered LDS V + one-tap-ahead offset prefetch.
// Per-thread state shrunk for the 64-reg/wave cap at 8 waves/EU:
// pf[16] + acc[2](8 AGPR) + tap/misc ~ 45 live. LDS 2x4736B x8 = 75.8KB.
__launch_bounds__(256, 8)
__global__ void dcn_mfma(const _Float16* __restrict__ xn,   // NHWC fp16
                         const float* __restrict__ offset,
                         const unsigned short* __restrict__ wb,
                         const float* __restrict__ bias,
                         float* __restrict__ out) {
    __shared__ unsigned short V[2][32 * VP];   // 2 x 4736 B

    const int tid = threadIdx.x;
    const int p   = tid >> 3;     // position (gather role): 8 lanes share one pos
    const int cg  = tid & 7;      // channel chunk 8ch = 16B
    const int wv  = tid >> 6;     // wave id (MFMA role)
    const int ln  = tid & 63;

    const int b  = blockIdx.z;
    const int h  = blockIdx.y;
    const int w0 = blockIdx.x * 32;
    const int w  = w0 + p;

    const uint4* xb4  = (const uint4*)(xn + (size_t)b * HW * 64);
    const float* offb = offset + b * 18 * HW + h * Ww + w;
    unsigned short* vrow0 = &V[0][p * VP + cg * 8];
    unsigned short* vrow1 = &V[1][p * VP + cg * 8];

    floatx4 acc[2];
    acc[0] = (floatx4)0.f; acc[1] = (floatx4)0.f;

    unsigned pf[16];
    Tap t;

    // prologue: tap 0 (offset loads + gather exposed once)
    float dy = offb[0];
    float dx = offb[HW];
    float ndy = offb[2 * HW];   // prefetch tap 1 offsets
    float ndx = offb[3 * HW];
    tap_setup(0, h, w, dy, dx, cg, t);
    tap_load(xb4, t, pf);
    tap_store(t, pf, vrow0);
    __syncthreads();

    // pipeline: prefetch offsets kt+1, issue gathers kt, MFMA kt-1, pack kt
#pragma unroll 1
    for (int kt = 1; kt < 9; ++kt) {
        dy = ndy; dx = ndx;
        if (kt < 8) {
            ndy = offb[(2 * kt + 2) * HW];   // in flight across this whole tap
            ndx = offb[(2 * kt + 3) * HW];
        }
        tap_setup(kt, h, w, dy, dx, cg, t);
        tap_load(xb4, t, pf);                              // gathers in flight
        mfma_tap(wb + (kt - 1) * COUT * Cc, V[(kt - 1) & 1], wv, ln, acc);
        tap_store(t, pf, (kt & 1) ? vrow1 : vrow0);        // waits gathers here
        __syncthreads();
    }
    // epilogue: tap 8 MFMA (buffer 0)
    mfma_tap(wb + 8 * COUT * Cc, V[0], wv, ln, acc);

    // epilogue: C/D layout col=lane&15 (pos), row=(lane>>4)*4+reg (o)
    float* outp = out + b * COUT * HW + h * Ww;
    const int nt = wv & 1;
    const int mb = (wv >> 1) * 2;
    const int col = w0 + nt * 16 + (ln & 15);
#pragma unroll
    for (int mi = 0; mi < 2; ++mi)
#pragma unroll
        for (int r = 0; r < 4; ++r) {
            const int o = (mb + mi) * 16 + (ln >> 4) * 4 + r;
            outp[o * HW + col] = acc[mi][r] + bias[o];
        }
}

extern "C" void kernel_launch(void* const* d_in, const int* in_sizes, int n_in,
                              void* d_out, int out_size, void* d_ws, size_t ws_size,
                              hipStream_t stream) {
    const float* x      = (const float*)d_in[0];
    const float* offset = (const float*)d_in[1];
    const float* weight = (const float*)d_in[2];
    const float* bias   = (const float*)d_in[3];
    float* out = (float*)d_out;

    _Float16* xn = (_Float16*)d_ws;                          // 16.8 MiB NHWC fp16
    unsigned short* wb = (unsigned short*)((char*)d_ws + (size_t)Bb * HW * Cc * 2);

    wtrans<<<dim3((COUT * Cc * 9 + 255) / 256), 256, 0, stream>>>(weight, wb);
    xtrans<<<dim3(2, Hh, Bb), 256, 0, stream>>>(x, xn);
    dcn_mfma<<<dim3(Ww / 32, Hh, Bb), 256, 0, stream>>>(xn, offset, wb, bias, out);
}

// Round 10
// 179.153 us; speedup vs baseline: 1.3906x; 1.0119x over previous
//
#include <hip/hip_runtime.h>

typedef float floatx4 __attribute__((ext_vector_type(4)));
typedef _Float16 half2v __attribute__((ext_vector_type(2)));
typedef _Float16 half8 __attribute__((ext_vector_type(8)));

#define Hh 128
#define Ww 256
#define Cc 64
#define COUT 64
#define Bb 4
#define HW (Hh*Ww)
#define VP 74   // LDS V row stride in shorts: 37 dwords ≡ 5 (mod 32) -> <=2-way (free)

// weight (o, c, kt) fp32 -> Wh[kt][o][c] fp16 (A-operand friendly: c contiguous)
__global__ void wtrans(const float* __restrict__ src, unsigned short* __restrict__ dst) {
    int i = blockIdx.x * 256 + threadIdx.x;
    if (i >= COUT * Cc * 9) return;
    int kt = i % 9, c = (i / 9) % Cc, o = i / (9 * Cc);
    _Float16 hv = (_Float16)src[i];
    dst[(kt * COUT + o) * Cc + c] = *(unsigned short*)&hv;
}

// x NCHW fp32 -> NHWC fp16. Block = (wh, h, b): 128 positions x 64 ch.
__global__ void xtrans(const float* __restrict__ src, _Float16* __restrict__ dst) {
    __shared__ unsigned short T[128][VP];
    const int wh = blockIdx.x, h = blockIdx.y, b = blockIdx.z;
    const int tid = threadIdx.x;
    const int wl = tid & 127;           // position within half-row
    const int ch = tid >> 7;            // channel half (32 ch each)
    const float* sp = src + ((b * Cc + ch * 32) * Hh + h) * Ww + wh * 128 + wl;
#pragma unroll
    for (int c2 = 0; c2 < 16; ++c2) {
        const float v0 = sp[(2 * c2) * HW];
        const float v1 = sp[(2 * c2 + 1) * HW];
        half2v hv; hv.x = (_Float16)v0; hv.y = (_Float16)v1;
        *(unsigned*)&T[wl][ch * 32 + 2 * c2] = *(unsigned*)&hv;
    }
    __syncthreads();
    uint4* drow = (uint4*)(dst + ((size_t)(b * Hh + h) * Ww + wh * 128) * 64);  // 1024 uint4
#pragma unroll
    for (int j = 0; j < 4; ++j) {
        const int idx = j * 256 + tid;        // contiguous 4KB per iteration
        drow[idx] = *(const uint4*)&T[idx >> 3][(idx & 7) * 8];
    }
}

// Raw barrier: lgkmcnt(0) only (LDS visibility), NO vmcnt drain -> in-flight
// gathers survive the barrier (the compiler's __syncthreads drains vmcnt(0)).
__device__ __forceinline__ void lds_barrier() {
    asm volatile("s_waitcnt lgkmcnt(0)\n\ts_barrier" ::: "memory");
}

struct Tap {
    half2v W00, W01, W10, W11;   // packed (w,w) fp16 corner weights
    int a00, a01, a10, a11;      // corner addresses in uint4 (16B) units
};

__device__ __forceinline__ void tap_setup(int kt, int h, int w, float dy, float dx,
                                          int cg, Tap& t) {
    const int ki = kt / 3, kj = kt % 3;
    const float py = (float)(h - 1 + ki) + dy;
    const float px = (float)(w - 1 + kj) + dx;
    const float y0f = floorf(py), x0f = floorf(px);
    const int y0 = (int)y0f, x0 = (int)x0f;
    const float ly = py - y0f, lx = px - x0f;
    const int y1 = y0 + 1, x1 = x0 + 1;
    const bool vy0 = ((unsigned)y0 < Hh), vy1 = ((unsigned)y1 < Hh);
    const bool vx0 = ((unsigned)x0 < Ww), vx1 = ((unsigned)x1 < Ww);
    const float w00 = (vy0 && vx0) ? (1.f - ly) * (1.f - lx) : 0.f;
    const float w01 = (vy0 && vx1) ? (1.f - ly) * lx : 0.f;
    const float w10 = (vy1 && vx0) ? ly * (1.f - lx) : 0.f;
    const float w11 = (vy1 && vx1) ? ly * lx : 0.f;
    _Float16 h00 = (_Float16)w00, h01 = (_Float16)w01;
    _Float16 h10 = (_Float16)w10, h11 = (_Float16)w11;
    t.W00.x = h00; t.W00.y = h00;  t.W01.x = h01; t.W01.y = h01;
    t.W10.x = h10; t.W10.y = h10;  t.W11.x = h11; t.W11.y = h11;
    const int y0c = min(max(y0, 0), Hh - 1), y1c = min(max(y1, 0), Hh - 1);
    const int x0c = min(max(x0, 0), Ww - 1), x1c = min(max(x1, 0), Ww - 1);
    t.a00 = (y0c * Ww + x0c) * 8 + cg;   // 64ch*2B = 8 uint4/pos; cg = 1 uint4 (8ch)
    t.a01 = (y0c * Ww + x1c) * 8 + cg;
    t.a10 = (y1c * Ww + x0c) * 8 + cg;
    t.a11 = (y1c * Ww + x1c) * 8 + cg;
}

// 4 x 16B loads: 8 adjacent lanes (same p, cg=0..7) cover a contiguous 128B row
__device__ __forceinline__ void tap_load(const uint4* __restrict__ xb4, const Tap& t,
                                         unsigned (&pf)[16]) {
    *(uint4*)&pf[0]  = xb4[t.a00];
    *(uint4*)&pf[4]  = xb4[t.a01];
    *(uint4*)&pf[8]  = xb4[t.a10];
    *(uint4*)&pf[12] = xb4[t.a11];
}

// packed-fp16 bilinear combine: 4 pk-FMAs per 2 channels
__device__ __forceinline__ void tap_store(const Tap& t, const unsigned (&pf)[16],
                                          unsigned short* __restrict__ vrow) {
    unsigned o[4];
#pragma unroll
    for (int s = 0; s < 4; ++s) {
        half2v v = (*(const half2v*)&pf[s])      * t.W00
                 + (*(const half2v*)&pf[4 + s])  * t.W01
                 + (*(const half2v*)&pf[8 + s])  * t.W10
                 + (*(const half2v*)&pf[12 + s]) * t.W11;
        o[s] = *(unsigned*)&v;
    }
    uint4 u; u.x = o[0]; u.y = o[1]; u.z = o[2]; u.w = o[3];
    *(uint4*)vrow = u;   // single ds_write_b128 (8 channels)
}

// Wave wv: n-tile nt = wv&1 (16 pos), m-tiles (wv>>1)*2 + {0,1}
__device__ __forceinline__ void mfma_tap(const unsigned short* __restrict__ wk,
                                         const unsigned short* __restrict__ Vbuf,
                                         int wv, int ln, floatx4 (&acc)[2]) {
    const int nt = wv & 1;
    const int mb = (wv >> 1) * 2;
#pragma unroll
    for (int g = 0; g < 2; ++g) {
        const int pp = nt * 16 + (ln & 15);
        half8 bfrag = *(const half8*)&Vbuf[pp * VP + g * 32 + (ln >> 4) * 8];
#pragma unroll
        for (int mi = 0; mi < 2; ++mi) {
            const int oo = (mb + mi) * 16 + (ln & 15);
            half8 afrag = *(const half8*)(wk + oo * Cc + g * 32 + (ln >> 4) * 8);
            acc[mi] = __builtin_amdgcn_mfma_f32_16x16x32_f16(afrag, bfrag, acc[mi], 0, 0, 0);
        }
    }
}

// One steady-state pipeline iteration, compile-time KT (1..8):
//   setup(KT+1) -> mfma(KT-1) [wfrag loads drain pfS, needed next anyway]
//   -> issue gathers(KT+1) [newest: survive all older waits]
//   -> store(KT) [vmcnt leaves pfT in flight] -> offset refill -> raw barrier
template<int KT>
__device__ __forceinline__ void pipe_iter(
    const uint4* __restrict__ xb4, const float* __restrict__ offb,
    const unsigned short* __restrict__ wb,
    const unsigned short* __restrict__ Vb0, const unsigned short* __restrict__ Vb1,
    unsigned short* __restrict__ vrow0, unsigned short* __restrict__ vrow1,
    int h, int w, int cg, int wv, int ln,
    Tap& tp0, Tap& tp1, unsigned (&pf0)[16], unsigned (&pf1)[16],
    float& dy0, float& dx0, float& dy1, float& dx1,
    floatx4 (&acc)[2])
{
    constexpr int S = KT & 1, T = 1 - S;
    Tap& tpS = S ? tp1 : tp0;
    Tap& tpT = S ? tp0 : tp1;
    unsigned (&pfS)[16] = S ? pf1 : pf0;
    unsigned (&pfT)[16] = S ? pf0 : pf1;

    if constexpr (KT < 8) {
        const float dyn = T ? dy1 : dy0;
        const float dxn = T ? dx1 : dx0;
        tap_setup(KT + 1, h, w, dyn, dxn, cg, tpT);
    }
    mfma_tap(wb + (KT - 1) * COUT * Cc, T ? Vb1 : Vb0, wv, ln, acc);
    if constexpr (KT < 8) tap_load(xb4, tpT, pfT);       // issue last -> survives waits
    tap_store(tpS, pfS, S ? vrow1 : vrow0);
    if constexpr (KT + 3 <= 8) {                          // refill P[T] with tap KT+3
        (T ? dy1 : dy0) = offb[(2 * (KT + 3)) * HW];
        (T ? dx1 : dx0) = offb[(2 * (KT + 3) + 1) * HW];
    }
    lds_barrier();
}

// Implicit GEMM, 32-pos tiles (4096 blocks), 2-tap-deep gather pipeline,
// packed-fp16 combine, raw lgkm-only barrier, double-buffered LDS V.
// (256,6): reg est ~70 < 85 cap; LDS 9.5KB -> not limiting.
__launch_bounds__(256, 6)
__global__ void dcn_mfma(const _Float16* __restrict__ xn,   // NHWC fp16
                         const float* __restrict__ offset,
                         const unsigned short* __restrict__ wb,
                         const float* __restrict__ bias,
                         float* __restrict__ out) {
    __shared__ unsigned short V[2][32 * VP];   // 2 x 4736 B

    const int tid = threadIdx.x;
    const int p   = tid >> 3;     // position (gather role): 8 lanes share one pos
    const int cg  = tid & 7;      // channel chunk 8ch = 16B
    const int wv  = tid >> 6;     // wave id (MFMA role)
    const int ln  = tid & 63;

    const int b  = blockIdx.z;
    const int h  = blockIdx.y;
    const int w0 = blockIdx.x * 32;
    const int w  = w0 + p;

    const uint4* xb4  = (const uint4*)(xn + (size_t)b * HW * 64);
    const float* offb = offset + b * 18 * HW + h * Ww + w;
    unsigned short* vrow0 = &V[0][p * VP + cg * 8];
    unsigned short* vrow1 = &V[1][p * VP + cg * 8];

    floatx4 acc[2];
    acc[0] = (floatx4)0.f; acc[1] = (floatx4)0.f;

    unsigned pf0[16], pf1[16];
    Tap tp0, tp1;

    // prologue: taps 0 and 1 both in flight; store tap 0
    float dy0 = offb[0],        dx0 = offb[HW];
    float dy1 = offb[2 * HW],   dx1 = offb[3 * HW];
    tap_setup(0, h, w, dy0, dx0, cg, tp0);
    tap_load(xb4, tp0, pf0);
    tap_setup(1, h, w, dy1, dx1, cg, tp1);
    tap_load(xb4, tp1, pf1);
    dy0 = offb[4 * HW]; dx0 = offb[5 * HW];   // tap2 (consumed at KT=1)
    dy1 = offb[6 * HW]; dx1 = offb[7 * HW];   // tap3 (consumed at KT=2)
    tap_store(tp0, pf0, vrow0);               // waits only pf0 (older than pf1)
    lds_barrier();

#define PI(K) pipe_iter<K>(xb4, offb, wb, V[0], V[1], vrow0, vrow1, h, w, cg, wv, ln, \
                           tp0, tp1, pf0, pf1, dy0, dx0, dy1, dx1, acc)
    PI(1); PI(2); PI(3); PI(4); PI(5); PI(6); PI(7); PI(8);
#undef PI

    // epilogue: tap 8 MFMA (V[0])
    mfma_tap(wb + 8 * COUT * Cc, V[0], wv, ln, acc);

    // epilogue: C/D layout col=lane&15 (pos), row=(lane>>4)*4+reg (o)
    float* outp = out + b * COUT * HW + h * Ww;
    const int nt = wv & 1;
    const int mb = (wv >> 1) * 2;
    const int col = w0 + nt * 16 + (ln & 15);
#pragma unroll
    for (int mi = 0; mi < 2; ++mi)
#pragma unroll
        for (int r = 0; r < 4; ++r) {
            const int o = (mb + mi) * 16 + (ln >> 4) * 4 + r;
            outp[o * HW + col] = acc[mi][r] + bias[o];
        }
}

extern "C" void kernel_launch(void* const* d_in, const int* in_sizes, int n_in,
                              void* d_out, int out_size, void* d_ws, size_t ws_size,
                              hipStream_t stream) {
    const float* x      = (const float*)d_in[0];
    const float* offset = (const float*)d_in[1];
    const float* weight = (const float*)d_in[2];
    const float* bias   = (const float*)d_in[3];
    float* out = (float*)d_out;

    _Float16* xn = (_Float16*)d_ws;                          // 16.8 MiB NHWC fp16
    unsigned short* wb = (unsigned short*)((char*)d_ws + (size_t)Bb * HW * Cc * 2);

    wtrans<<<dim3((COUT * Cc * 9 + 255) / 256), 256, 0, stream>>>(weight, wb);
    xtrans<<<dim3(2, Hh, Bb), 256, 0, stream>>>(x, xn);
    dcn_mfma<<<dim3(Ww / 32, Hh, Bb), 256, 0, stream>>>(xn, offset, wb, bias, out);
}

// Round 11
// 176.321 us; speedup vs baseline: 1.4129x; 1.0161x over previous
//
#include <hip/hip_runtime.h>

typedef float floatx4 __attribute__((ext_vector_type(4)));
typedef _Float16 half2v __attribute__((ext_vector_type(2)));
typedef _Float16 half8 __attribute__((ext_vector_type(8)));

#define Hh 128
#define Ww 256
#define Cc 64
#define COUT 64
#define Bb 4
#define HW (Hh*Ww)
#define VP 74   // LDS V row stride in shorts: 37 dwords ≡ 5 (mod 32) -> <=2-way (free)

// Combined prep: bx<2 -> x NCHW fp32 -> NHWC fp16 (as before);
// bx==2 -> weight (o,c,kt) fp32 -> fp16 [kt][o][c] (72 elements per block).
__global__ void prep(const float* __restrict__ x, const float* __restrict__ wsrc,
                     _Float16* __restrict__ xn, unsigned short* __restrict__ wdst) {
    const int bx = blockIdx.x, h = blockIdx.y, b = blockIdx.z;
    const int tid = threadIdx.x;
    if (bx == 2) {
        const int i = (h + Hh * b) * 72 + tid;
        if (tid < 72) {   // 512 blocks x 72 = 36864 = 9*64*64
            const int kt = i % 9, c = (i / 9) % Cc, o = i / (9 * Cc);
            _Float16 hv = (_Float16)wsrc[i];
            wdst[(kt * COUT + o) * Cc + c] = *(unsigned short*)&hv;
        }
        return;
    }
    __shared__ unsigned short T[128][VP];
    const int wl = tid & 127;           // position within half-row
    const int ch = tid >> 7;            // channel half (32 ch each)
    const float* sp = x + ((b * Cc + ch * 32) * Hh + h) * Ww + bx * 128 + wl;
#pragma unroll
    for (int c2 = 0; c2 < 16; ++c2) {
        const float v0 = sp[(2 * c2) * HW];
        const float v1 = sp[(2 * c2 + 1) * HW];
        half2v hv; hv.x = (_Float16)v0; hv.y = (_Float16)v1;
        *(unsigned*)&T[wl][ch * 32 + 2 * c2] = *(unsigned*)&hv;
    }
    __syncthreads();
    uint4* drow = (uint4*)(xn + ((size_t)(b * Hh + h) * Ww + bx * 128) * 64);
#pragma unroll
    for (int j = 0; j < 4; ++j) {
        const int idx = j * 256 + tid;        // contiguous 4KB per iteration
        drow[idx] = *(const uint4*)&T[idx >> 3][(idx & 7) * 8];
    }
}

// Raw barrier: lgkmcnt(0) only (LDS visibility), NO vmcnt drain -> in-flight
// global loads survive the barrier.
__device__ __forceinline__ void lds_barrier() {
    asm volatile("s_waitcnt lgkmcnt(0)\n\ts_barrier" ::: "memory");
}

struct Tap {
    half2v W00, W01, W10, W11;   // packed (w,w) fp16 corner weights
    int a00, a01, a10, a11;      // corner addresses in uint4 (16B) units
};

__device__ __forceinline__ void tap_setup(int kt, int h, int w, float dy, float dx,
                                          int cg, Tap& t) {
    const int ki = kt / 3, kj = kt % 3;
    const float py = (float)(h - 1 + ki) + dy;
    const float px = (float)(w - 1 + kj) + dx;
    const float y0f = floorf(py), x0f = floorf(px);
    const int y0 = (int)y0f, x0 = (int)x0f;
    const float ly = py - y0f, lx = px - x0f;
    const int y1 = y0 + 1, x1 = x0 + 1;
    const bool vy0 = ((unsigned)y0 < Hh), vy1 = ((unsigned)y1 < Hh);
    const bool vx0 = ((unsigned)x0 < Ww), vx1 = ((unsigned)x1 < Ww);
    const float w00 = (vy0 && vx0) ? (1.f - ly) * (1.f - lx) : 0.f;
    const float w01 = (vy0 && vx1) ? (1.f - ly) * lx : 0.f;
    const float w10 = (vy1 && vx0) ? ly * (1.f - lx) : 0.f;
    const float w11 = (vy1 && vx1) ? ly * lx : 0.f;
    _Float16 h00 = (_Float16)w00, h01 = (_Float16)w01;
    _Float16 h10 = (_Float16)w10, h11 = (_Float16)w11;
    t.W00.x = h00; t.W00.y = h00;  t.W01.x = h01; t.W01.y = h01;
    t.W10.x = h10; t.W10.y = h10;  t.W11.x = h11; t.W11.y = h11;
    const int y0c = min(max(y0, 0), Hh - 1), y1c = min(max(y1, 0), Hh - 1);
    const int x0c = min(max(x0, 0), Ww - 1), x1c = min(max(x1, 0), Ww - 1);
    t.a00 = (y0c * Ww + x0c) * 8 + cg;   // 8 uint4/pos; cg = 1 uint4 (8ch)
    t.a01 = (y0c * Ww + x1c) * 8 + cg;
    t.a10 = (y1c * Ww + x0c) * 8 + cg;
    t.a11 = (y1c * Ww + x1c) * 8 + cg;
}

__device__ __forceinline__ void tap_load(const uint4* __restrict__ xb4, const Tap& t,
                                         unsigned (&pf)[16]) {
    *(uint4*)&pf[0]  = xb4[t.a00];
    *(uint4*)&pf[4]  = xb4[t.a01];
    *(uint4*)&pf[8]  = xb4[t.a10];
    *(uint4*)&pf[12] = xb4[t.a11];
}

// weight a-fragments for one tap (this wave's 2 m-tiles x 2 k-groups)
__device__ __forceinline__ void wf_load(const unsigned short* __restrict__ wt,
                                        half8 (&WF)[4]) {
    WF[0] = *(const half8*)(wt);                 // g0, mi0
    WF[1] = *(const half8*)(wt + 16 * Cc);       // g0, mi1
    WF[2] = *(const half8*)(wt + 32);            // g1, mi0
    WF[3] = *(const half8*)(wt + 16 * Cc + 32);  // g1, mi1
}

__device__ __forceinline__ void tap_store(const Tap& t, const unsigned (&pf)[16],
                                          unsigned short* __restrict__ vrow) {
    unsigned o[4];
#pragma unroll
    for (int s = 0; s < 4; ++s) {
        half2v v = (*(const half2v*)&pf[s])      * t.W00
                 + (*(const half2v*)&pf[4 + s])  * t.W01
                 + (*(const half2v*)&pf[8 + s])  * t.W10
                 + (*(const half2v*)&pf[12 + s]) * t.W11;
        o[s] = *(unsigned*)&v;
    }
    uint4 u; u.x = o[0]; u.y = o[1]; u.z = o[2]; u.w = o[3];
    *(uint4*)vrow = u;   // single ds_write_b128 (8 channels)
}

__device__ __forceinline__ void mfma_tap(const half8 (&WF)[4],
                                         const unsigned short* __restrict__ Vbuf,
                                         int nt, int ln, floatx4 (&acc)[2]) {
#pragma unroll
    for (int g = 0; g < 2; ++g) {
        const int pp = nt * 16 + (ln & 15);
        half8 bfrag = *(const half8*)&Vbuf[pp * VP + g * 32 + (ln >> 4) * 8];
        acc[0] = __builtin_amdgcn_mfma_f32_16x16x32_f16(WF[2 * g],     bfrag, acc[0], 0, 0, 0);
        acc[1] = __builtin_amdgcn_mfma_f32_16x16x32_f16(WF[2 * g + 1], bfrag, acc[1], 0, 0, 0);
    }
}

// Steady-state iteration KT (1..8). Issue order is the contract:
//   WF(KT) first -> G(KT+1) -> off(KT+3) -> mfma(KT-1) [waits WF(KT-1),
//   leaves this iter's loads in flight] -> store(KT) [waits G(KT), leaves
//   WF(KT)/G(KT+1) in flight] -> lgkm barrier. No same-iter VMEM waits.
template<int KT>
__device__ __forceinline__ void pipe_iter(
    const uint4* __restrict__ xb4, const float* __restrict__ offb,
    const unsigned short* __restrict__ wfb,
    const unsigned short* __restrict__ V0, const unsigned short* __restrict__ V1,
    unsigned short* __restrict__ vrow0, unsigned short* __restrict__ vrow1,
    int h, int w, int cg, int nt, int ln,
    Tap& tp0, Tap& tp1, unsigned (&pf0)[16], unsigned (&pf1)[16],
    half8 (&WF0)[4], half8 (&WF1)[4],
    float& dy0, float& dx0, float& dy1, float& dx1,
    floatx4 (&acc)[2])
{
    constexpr int S = KT & 1, T = 1 - S;
    // 1. prefetch weight frags for tap KT (consumed next iter / epilogue)
    wf_load(wfb + KT * COUT * Cc, S ? WF1 : WF0);
    // 2+3. setup & issue gathers for tap KT+1
    if constexpr (KT < 8) {
        tap_setup(KT + 1, h, w, T ? dy1 : dy0, T ? dx1 : dx0, cg, T ? tp1 : tp0);
        tap_load(xb4, T ? tp1 : tp0, T ? pf1 : pf0);
    }
    // 4. offset refill for tap KT+3 (same slot parity as KT+1, just consumed)
    if constexpr (KT + 3 <= 8) {
        (T ? dy1 : dy0) = offb[(2 * (KT + 3)) * HW];
        (T ? dx1 : dx0) = offb[(2 * (KT + 3) + 1) * HW];
    }
    // 5. MFMA tap KT-1 (weights preloaded last iter, V from last iter's store)
    mfma_tap(T ? WF1 : WF0, T ? V1 : V0, nt, ln, acc);
    // 6. combine+pack tap KT into V[KT&1]
    tap_store(S ? tp1 : tp0, S ? pf1 : pf0, S ? vrow1 : vrow0);
    // 7. barrier (lgkm only; VMEM prefetches stay in flight)
    lds_barrier();
}

// Implicit GEMM, 32-pos tiles (4096 blocks), fully software-pipelined:
// gathers, weight frags, and offsets all register-double-buffered with
// >= 1 full iteration of latency cover. (256,4): reg est ~106 < 128 cap.
__launch_bounds__(256, 4)
__global__ void dcn_mfma(const _Float16* __restrict__ xn,   // NHWC fp16
                         const float* __restrict__ offset,
                         const unsigned short* __restrict__ wb,
                         const float* __restrict__ bias,
                         float* __restrict__ out) {
    __shared__ unsigned short V[2][32 * VP];   // 2 x 4736 B

    const int tid = threadIdx.x;
    const int p   = tid >> 3;     // position (gather role): 8 lanes share one pos
    const int cg  = tid & 7;      // channel chunk 8ch = 16B
    const int wv  = tid >> 6;     // wave id (MFMA role)
    const int ln  = tid & 63;

    const int b  = blockIdx.z;
    const int h  = blockIdx.y;
    const int w0 = blockIdx.x * 32;
    const int w  = w0 + p;

    const uint4* xb4  = (const uint4*)(xn + (size_t)b * HW * 64);
    const float* offb = offset + b * 18 * HW + h * Ww + w;
    unsigned short* vrow0 = &V[0][p * VP + cg * 8];
    unsigned short* vrow1 = &V[1][p * VP + cg * 8];

    const int nt = wv & 1;
    const int mb = (wv >> 1) * 2;
    // per-wave weight fragment base: o = mb*16 + (ln&15), k-subgroup (ln>>4)*8
    const unsigned short* wfb = wb + (mb * 16 + (ln & 15)) * Cc + (ln >> 4) * 8;

    floatx4 acc[2];
    acc[0] = (floatx4)0.f; acc[1] = (floatx4)0.f;

    unsigned pf0[16], pf1[16];
    half8 WF0[4], WF1[4];
    Tap tp0, tp1;

    // prologue: offsets taps 0..3; WF(0); gathers taps 0,1; store tap 0
    float dy0 = offb[0],        dx0 = offb[HW];
    float dy1 = offb[2 * HW],   dx1 = offb[3 * HW];
    wf_load(wfb, WF0);                        // tap 0 -> WF0
    tap_setup(0, h, w, dy0, dx0, cg, tp0);
    tap_load(xb4, tp0, pf0);
    tap_setup(1, h, w, dy1, dx1, cg, tp1);
    tap_load(xb4, tp1, pf1);
    dy0 = offb[4 * HW]; dx0 = offb[5 * HW];   // tap 2 -> slot 0
    dy1 = offb[6 * HW]; dx1 = offb[7 * HW];   // tap 3 -> slot 1
    tap_store(tp0, pf0, vrow0);               // waits G(0); G(1) stays in flight
    lds_barrier();

#define PI(K) pipe_iter<K>(xb4, offb, wfb, V[0], V[1], vrow0, vrow1, h, w, cg, nt, ln, \
                           tp0, tp1, pf0, pf1, WF0, WF1, dy0, dx0, dy1, dx1, acc)
    PI(1); PI(2); PI(3); PI(4); PI(5); PI(6); PI(7); PI(8);
#undef PI

    // epilogue: tap 8 MFMA (WF0 = tap8 loaded at PI(8), V[0] stored at PI(8))
    mfma_tap(WF0, V[0], nt, ln, acc);

    // epilogue: C/D layout col=lane&15 (pos), row=(lane>>4)*4+reg (o)
    float* outp = out + b * COUT * HW + h * Ww;
    const int col = w0 + nt * 16 + (ln & 15);
#pragma unroll
    for (int mi = 0; mi < 2; ++mi)
#pragma unroll
        for (int r = 0; r < 4; ++r) {
            const int o = (mb + mi) * 16 + (ln >> 4) * 4 + r;
            outp[o * HW + col] = acc[mi][r] + bias[o];
        }
}

extern "C" void kernel_launch(void* const* d_in, const int* in_sizes, int n_in,
                              void* d_out, int out_size, void* d_ws, size_t ws_size,
                              hipStream_t stream) {
    const float* x      = (const float*)d_in[0];
    const float* offset = (const float*)d_in[1];
    const float* weight = (const float*)d_in[2];
    const float* bias   = (const float*)d_in[3];
    float* out = (float*)d_out;

    _Float16* xn = (_Float16*)d_ws;                          // 16.8 MiB NHWC fp16
    unsigned short* wb = (unsigned short*)((char*)d_ws + (size_t)Bb * HW * Cc * 2);

    prep<<<dim3(3, Hh, Bb), 256, 0, stream>>>(x, weight, xn, wb);
    dcn_mfma<<<dim3(Ww / 32, Hh, Bb), 256, 0, stream>>>(xn, offset, wb, bias, out);
}